// Round 1
// baseline (334.232 us; speedup 1.0000x reference)
//
#include <hip/hip_runtime.h>
#include <hip/hip_bf16.h>

// Problem constants
#define B_ROWS 16384
#define K_DIM  1024
#define N_INT  1023
#define N_OUT  1000

using s8vec = __attribute__((ext_vector_type(8))) short;   // 8 bf16 (4 VGPRs) MFMA operand
using f32x4 = __attribute__((ext_vector_type(4))) float;   // MFMA accumulator

// Workspace layout (bytes). Total ~105 MB.
static const size_t OFF_XB   = 0;                        // bf16 [16384*1024]
static const size_t OFF_W1   = OFF_XB   + 33554432;      // bf16 [1024*1024] (row 1023 = 0)
static const size_t OFF_BIAS = OFF_W1   + 2097152;       // f32  [1024]
static const size_t OFF_PROB = OFF_BIAS + 4096;          // bf16 [16384*1024] (col 1023 unused)
static const size_t OFF_PATH = OFF_PROB + 33554432;      // bf16 [16384*1024]
static const size_t OFF_W2   = OFF_PATH + 33554432;      // bf16 [1024*1024] (rows >=1000 = 0)
static const size_t OFF_S1   = OFF_W2   + 2097152;       // f32  [1024] (1023 used)
static const size_t OFF_S2   = OFF_S1   + 4096;          // f32  [1024]

__device__ __forceinline__ float b2f(ushort u) {
  return __uint_as_float(((unsigned)u) << 16);
}
__device__ __forceinline__ ushort f2b(float f) {
  unsigned u = __float_as_uint(f);
  u = u + 0x7FFFu + ((u >> 16) & 1u);   // RNE
  return (ushort)(u >> 16);
}

// ---------------- converts ----------------
__global__ __launch_bounds__(256) void cvt_x(const float4* __restrict__ X,
                                             ushort4* __restrict__ O) {
  const int i = blockIdx.x * 256 + threadIdx.x;   // grid sized exactly
  const float4 v = X[i];
  ushort4 o;
  o.x = f2b(v.x); o.y = f2b(v.y); o.z = f2b(v.z); o.w = f2b(v.w);
  O[i] = o;
}

__global__ __launch_bounds__(256) void cvt_w1(const float* __restrict__ W,
                                              ushort* __restrict__ W1,
                                              float* __restrict__ bias) {
  const int idx = blockIdx.x * 256 + threadIdx.x;   // 1024*1024 threads
  const int n = idx >> 10, k = idx & 1023;
  const float v = (n < N_INT) ? W[n * 1025 + 1 + k] : 0.f;
  W1[idx] = f2b(v);
  if (k == 0) bias[n] = (n < N_INT) ? W[n * 1025] : 0.f;
}

__global__ __launch_bounds__(256) void cvt_w2(const float* __restrict__ W,
                                              ushort* __restrict__ W2) {
  const int idx = blockIdx.x * 256 + threadIdx.x;   // 1024*1024 threads
  const int n = idx >> 10, k = idx & 1023;
  const float v = (n < N_OUT) ? W[n * 1024 + k] : 0.f;
  W2[idx] = f2b(v);
}

// ---------------- GEMM: C = A[M,K] * Bm[N,K]^T, 128x128 tile, 4 waves ----------------
// MODE 0: epilogue sigmoid(acc + bias[n]) -> bf16 probs [M,1024]
// MODE 1: epilogue store f32 to out [M,1000] (guard n<1000)
template <int MODE>
__global__ __launch_bounds__(256) void gemm_bt(const ushort* __restrict__ A,
                                               const ushort* __restrict__ Bm,
                                               const float* __restrict__ bias,
                                               void* __restrict__ outp) {
  __shared__ ushort As[4096];   // [128 rows][32 cols] bf16
  __shared__ ushort Bs[4096];
  const int tid = threadIdx.x;
  const int bn = blockIdx.x, bm = blockIdx.y;
  const int lane = tid & 63, wv = tid >> 6;
  const int wm = wv >> 1, wn = wv & 1;
  const int m16 = lane & 15, q = lane >> 4;

  // staging: thread t handles 16B chunks t and t+256; chunk c -> row c>>2, colgrp c&3
  const ushort* a0p = A  + (size_t)(bm * 128 + (tid >> 2)) * 1024 + (tid & 3) * 8;
  const ushort* b0p = Bm + (size_t)(bn * 128 + (tid >> 2)) * 1024 + (tid & 3) * 8;

  f32x4 acc[4][4] = {};

  for (int k0 = 0; k0 < 1024; k0 += 32) {
    *(uint4*)(As + tid * 8)        = *(const uint4*)(a0p + k0);
    *(uint4*)(As + 2048 + tid * 8) = *(const uint4*)(a0p + 65536 + k0);  // +64 rows
    *(uint4*)(Bs + tid * 8)        = *(const uint4*)(b0p + k0);
    *(uint4*)(Bs + 2048 + tid * 8) = *(const uint4*)(b0p + 65536 + k0);
    __syncthreads();
    s8vec af[4], bfv[4];
#pragma unroll
    for (int i = 0; i < 4; ++i)
      af[i] = *(const s8vec*)(As + (wm * 64 + i * 16 + m16) * 32 + q * 8);
#pragma unroll
    for (int j = 0; j < 4; ++j)
      bfv[j] = *(const s8vec*)(Bs + (wn * 64 + j * 16 + m16) * 32 + q * 8);
#pragma unroll
    for (int i = 0; i < 4; ++i)
#pragma unroll
      for (int j = 0; j < 4; ++j)
        acc[i][j] = __builtin_amdgcn_mfma_f32_16x16x32_bf16(af[i], bfv[j], acc[i][j], 0, 0, 0);
    __syncthreads();
  }

  // C/D layout: col = lane&15, row = (lane>>4)*4 + r   [measured: learn_hip m89/m91]
  if (MODE == 0) {
    ushort* P = (ushort*)outp;
#pragma unroll
    for (int i = 0; i < 4; ++i)
#pragma unroll
      for (int r = 0; r < 4; ++r) {
        const int gr = bm * 128 + wm * 64 + i * 16 + q * 4 + r;
#pragma unroll
        for (int j = 0; j < 4; ++j) {
          const int gc = bn * 128 + wn * 64 + j * 16 + m16;
          const float z = acc[i][j][r] + bias[gc];
          const float p = 1.f / (1.f + expf(-z));
          P[(size_t)gr * 1024 + gc] = f2b(p);
        }
      }
  } else {
    float* O = (float*)outp;
#pragma unroll
    for (int i = 0; i < 4; ++i)
#pragma unroll
      for (int r = 0; r < 4; ++r) {
        const int gr = bm * 128 + wm * 64 + i * 16 + q * 4 + r;
#pragma unroll
        for (int j = 0; j < 4; ++j) {
          const int gc = bn * 128 + wn * 64 + j * 16 + m16;
          if (gc < N_OUT) O[(size_t)gr * 1000 + gc] = acc[i][j][r];
        }
      }
  }
}

// ---------------- tree: wave-per-row path products + S1/S2 reductions ----------------
// Per layer ell (n=2^ell nodes, probs start 2^ell-1):
//   pathnew[k] = pathold[k>>1] * (k&1 ? 1-P[k>>1] : P[k>>1]),  k in [0,2n)
//   S1[j] += pathnew[j];  S2[j] += P[j]*pathnew[j],  j in [0,n)   (reference's
//   "parent = updated path first half" quirk -> num[2j]=S2, num[2j+1]=S1-S2, den=S1)
__global__ __launch_bounds__(256) void tree_kernel(const ushort* __restrict__ probs,
                                                   ushort* __restrict__ path,
                                                   float* __restrict__ S1g,
                                                   float* __restrict__ S2g) {
  __shared__ float S1s[1023];
  __shared__ float S2s[1023];
  for (int i = threadIdx.x; i < 1023; i += 256) { S1s[i] = 0.f; S2s[i] = 0.f; }
  __syncthreads();
  const int lane = threadIdx.x & 63;
  const int gw = blockIdx.x * 4 + (threadIdx.x >> 6);   // 1024 waves total

  float at1[6] = {}, at2[6] = {};     // layers 0..5 (one slot/lane, most lanes unused)
  float ae1[30] = {}, ae2[30] = {};   // layers 6..9, lanes<32: 2+4+8+16 slots

  for (int r = gw; r < B_ROWS; r += 1024) {
    const ushort* prow = probs + (size_t)r * 1024;
    // prefix chain down to the size-64 layer; lane = entry index there
    float v = 1.f;
#pragma unroll
    for (int t = 1; t <= 6; ++t) {
      const int ell = t - 1;
      const int e = lane >> (6 - t);                       // entry at layer ell (size 2^t)
      const float p = b2f(prow[(1 << ell) - 1 + (e >> 1)]);
      v *= (e & 1) ? (1.f - p) : p;
      if (((lane & ((1 << (6 - t)) - 1)) == 0) && (e < (1 << ell))) {
        const float pj = b2f(prow[(1 << ell) - 1 + e]);
        at1[ell] += v;
        at2[ell] += pj * v;
      }
    }
    // lane-local register expansion 1 -> 16 leaves (blocked subtree layout)
    float w[16];
    w[0] = v;
#pragma unroll
    for (int ell = 6; ell <= 9; ++ell) {
      const int s = 1 << (ell - 6);       // old entries per lane
      const int pb = (1 << ell) - 1;      // probs base for this layer
#pragma unroll
      for (int i = s - 1; i >= 0; --i) {  // backward: in-place safe
        const float p = b2f(prow[pb + s * lane + i]);
        w[2 * i + 1] = w[i] * (1.f - p);
        w[2 * i]     = w[i] * p;
      }
      if (lane < 32) {                     // first-half entries live in lanes 0..31
        const int base = 2 * s - 2;
#pragma unroll
        for (int i = 0; i < 2 * s; ++i) {
          const int j = 2 * s * lane + i;
          const float pj = b2f(prow[pb + j]);
          ae1[base + i] += w[i];
          ae2[base + i] += pj * w[i];
        }
      }
    }
    // store 16 leaves (32B per lane, two 16B stores)
    union { ushort u[16]; uint4 q4[2]; } pk;
#pragma unroll
    for (int i = 0; i < 16; ++i) pk.u[i] = f2b(w[i]);
    uint4* dst = (uint4*)(path + (size_t)r * 1024 + lane * 16);
    dst[0] = pk.q4[0];
    dst[1] = pk.q4[1];
  }

  // merge register accumulators -> LDS
#pragma unroll
  for (int t = 1; t <= 6; ++t) {
    const int ell = t - 1;
    const int e = lane >> (6 - t);
    if (((lane & ((1 << (6 - t)) - 1)) == 0) && (e < (1 << ell))) {
      atomicAdd(&S1s[(1 << ell) - 1 + e], at1[ell]);
      atomicAdd(&S2s[(1 << ell) - 1 + e], at2[ell]);
    }
  }
  if (lane < 32) {
#pragma unroll
    for (int ell = 6; ell <= 9; ++ell) {
      const int s = 1 << (ell - 6);
      const int pb = (1 << ell) - 1;
      const int base = 2 * s - 2;
#pragma unroll
      for (int i = 0; i < 2 * s; ++i) {
        atomicAdd(&S1s[pb + 2 * s * lane + i], ae1[base + i]);
        atomicAdd(&S2s[pb + 2 * s * lane + i], ae2[base + i]);
      }
    }
  }
  __syncthreads();
  for (int i = threadIdx.x; i < 1023; i += 256) {
    atomicAdd(&S1g[i], S1s[i]);
    atomicAdd(&S2g[i], S2s[i]);
  }
}

// ---------------- finalize: alphas + log-regularizer ----------------
__global__ __launch_bounds__(1024) void finalize_kernel(const float* __restrict__ S1g,
                                                        const float* __restrict__ S2g,
                                                        float* __restrict__ outreg) {
  const int tid = threadIdx.x;
  double val = 0.0;
  if (tid < 1023) {
    const int ell = 31 - __clz(tid + 1);           // node tid is in layer ell
    const double s1 = (double)S1g[tid];
    const double s2 = (double)S2g[tid];
    const double den = s1 + 1e-8;
    const double a0 = s2 / den;                    // alpha for even child
    const double a1 = (s1 - s2) / den;             // alpha for odd child
    const double f = 1e-3 * (1.0 / (double)(1 << ell));
    val = -0.5 * f * (log(a0) + log(1.0 - a0) + log(a1) + log(1.0 - a1));
  }
#pragma unroll
  for (int o = 32; o > 0; o >>= 1) val += __shfl_down(val, o, 64);
  __shared__ double part[16];
  if ((tid & 63) == 0) part[tid >> 6] = val;
  __syncthreads();
  if (tid == 0) {
    double t = 0.0;
    for (int i = 0; i < 16; ++i) t += part[i];
    outreg[0] = (float)t;
  }
}

extern "C" void kernel_launch(void* const* d_in, const int* in_sizes, int n_in,
                              void* d_out, int out_size, void* d_ws, size_t ws_size,
                              hipStream_t stream) {
  const float* X     = (const float*)d_in[0];   // [16384,1024]
  const float* Wint  = (const float*)d_in[1];   // [1023,1025]
  const float* Wleaf = (const float*)d_in[2];   // [1000,1024]
  float* out = (float*)d_out;                   // [16384*1000] preds + [1] reg
  char* ws = (char*)d_ws;                       // needs ~105 MB

  ushort* Xb   = (ushort*)(ws + OFF_XB);
  ushort* W1   = (ushort*)(ws + OFF_W1);
  float*  bias = (float*)(ws + OFF_BIAS);
  ushort* prob = (ushort*)(ws + OFF_PROB);
  ushort* path = (ushort*)(ws + OFF_PATH);
  ushort* W2   = (ushort*)(ws + OFF_W2);
  float*  S1g  = (float*)(ws + OFF_S1);
  float*  S2g  = (float*)(ws + OFF_S2);

  (void)hipMemsetAsync(ws + OFF_S1, 0, 8192, stream);  // zero S1g+S2g
  cvt_x<<<16384, 256, 0, stream>>>((const float4*)X, (ushort4*)Xb);
  cvt_w1<<<4096, 256, 0, stream>>>(Wint, W1, bias);
  cvt_w2<<<4096, 256, 0, stream>>>(Wleaf, W2);
  gemm_bt<0><<<dim3(8, 128), 256, 0, stream>>>(Xb, W1, bias, (void*)prob);
  tree_kernel<<<256, 256, 0, stream>>>(prob, path, S1g, S2g);
  gemm_bt<1><<<dim3(8, 128), 256, 0, stream>>>(path, W2, nullptr, (void*)out);
  finalize_kernel<<<1, 1024, 0, stream>>>(S1g, S2g, out + (size_t)B_ROWS * N_OUT);
}